// Round 1
// baseline (506.895 us; speedup 1.0000x reference)
//
#include <hip/hip_runtime.h>
#include <cstdint>
#include <cstring>

typedef unsigned short u16;
typedef short bf16x8 __attribute__((ext_vector_type(8)));
typedef float f32x4 __attribute__((ext_vector_type(4)));

#define MFMA16(a,b,c) __builtin_amdgcn_mfma_f32_16x16x32_bf16(a,b,c,0,0,0)

// ---------- helpers ----------

__device__ __forceinline__ u16 f2bf(float f) {
  union { float f; uint32_t u; } un; un.f = f;
  uint32_t u = un.u;
  u += 0x7FFFu + ((u >> 16) & 1u);   // RNE
  return (u16)(u >> 16);
}

__device__ __forceinline__ void gl_lds16(const void* g, void* l) {
  __builtin_amdgcn_global_load_lds(
      (__attribute__((address_space(1))) void*)(const_cast<void*>(g)),
      (__attribute__((address_space(3))) void*)l, 16, 0, 0);
}

// ---------- weight transpose + f32->bf16 : W[K][N] -> Wt[N][K] ----------

__global__ __launch_bounds__(256) void transpose_to_bf16(
    const float* __restrict__ W, u16* __restrict__ Wt, int K, int N)
{
  __shared__ float tile[32][33];
  int kt = blockIdx.y * 32, nt = blockIdx.x * 32;
  int tx = threadIdx.x, ty = threadIdx.y;          // (32, 8)
#pragma unroll
  for (int i = 0; i < 4; ++i)
    tile[ty + i * 8][tx] = W[(size_t)(kt + ty + i * 8) * N + nt + tx];
  __syncthreads();
#pragma unroll
  for (int i = 0; i < 4; ++i)
    Wt[(size_t)(nt + ty + i * 8) * K + kt + tx] = f2bf(tile[tx][ty + i * 8]);
}

// ---------- LayerNorm (f32 in -> bf16 out), one block per row of 1024 ----------

__global__ __launch_bounds__(256) void ln_bf16(
    const float* __restrict__ x, const float* __restrict__ wt,
    const float* __restrict__ bs, u16* __restrict__ out)
{
  int row = blockIdx.x;
  int tid = threadIdx.x, lane = tid & 63, w = tid >> 6;
  const float* xr = x + (size_t)row * 1024;
  float4 v = *(const float4*)(xr + tid * 4);
  float s = v.x + v.y + v.z + v.w;
  float sq = v.x * v.x + v.y * v.y + v.z * v.z + v.w * v.w;
#pragma unroll
  for (int o = 1; o < 64; o <<= 1) { s += __shfl_xor(s, o); sq += __shfl_xor(sq, o); }
  __shared__ float ls[4], lq[4];
  if (lane == 0) { ls[w] = s; lq[w] = sq; }
  __syncthreads();
  s = ls[0] + ls[1] + ls[2] + ls[3];
  sq = lq[0] + lq[1] + lq[2] + lq[3];
  float mu = s * (1.f / 1024.f);
  float var = sq * (1.f / 1024.f) - mu * mu;
  float rstd = rsqrtf(var + 1e-5f);
  float4 wv = *(const float4*)(wt + tid * 4);
  float4 bv = *(const float4*)(bs + tid * 4);
  ushort4 o4;
  o4.x = f2bf((v.x - mu) * rstd * wv.x + bv.x);
  o4.y = f2bf((v.y - mu) * rstd * wv.y + bv.y);
  o4.z = f2bf((v.z - mu) * rstd * wv.z + bv.z);
  o4.w = f2bf((v.w - mu) * rstd * wv.w + bv.w);
  *(ushort4*)(out + (size_t)row * 1024 + tid * 4) = o4;
}

// ---------- GEMM mainloop: C(128x128) = A[M][K] @ Bt[N][K]^T, bf16 MFMA ----------
// 256 threads = 4 waves in 2x2; each wave 64x64 = 4x4 tiles of 16x16.

__device__ __forceinline__ void gemm_mainloop(
    const u16* __restrict__ A, const u16* __restrict__ Bt,
    int K, int m0, int n0, f32x4 acc[4][4])
{
  __shared__ __align__(16) u16 lA[128 * 32];
  __shared__ __align__(16) u16 lB[128 * 32];

  const int tid = threadIdx.x;
  const int lane = tid & 63;
  const int w = tid >> 6;
  const int wr = (w >> 1) * 64;
  const int wc = (w & 1) * 64;
  const int laneM = lane & 15;
  const int laneK = (lane >> 4) * 8;

#pragma unroll
  for (int i = 0; i < 4; ++i)
#pragma unroll
    for (int j = 0; j < 4; ++j)
      acc[i][j] = f32x4{0.f, 0.f, 0.f, 0.f};

  const int off0 = w * 1024 + lane * 16;   // byte offset within 8KB tile (pass 0)
  const int off1 = off0 + 4096;            // pass 1
  const int rA0 = off0 >> 6, cb0 = off0 & 63;
  const int rA1 = off1 >> 6, cb1 = off1 & 63;

  const size_t strideA = (size_t)K * 2;
  const char* gA = (const char*)(A + (size_t)m0 * K);
  const char* gB = (const char*)(Bt + (size_t)n0 * K);
  const char* pA0 = gA + (size_t)rA0 * strideA + cb0;
  const char* pA1 = gA + (size_t)rA1 * strideA + cb1;
  const char* pB0 = gB + (size_t)rA0 * strideA + cb0;
  const char* pB1 = gB + (size_t)rA1 * strideA + cb1;
  char* lA0 = (char*)lA + off0;
  char* lA1 = (char*)lA + off1;
  char* lB0 = (char*)lB + off0;
  char* lB1 = (char*)lB + off1;

  const u16* aRd = lA + (wr + laneM) * 32 + laneK;
  const u16* bRd = lB + (wc + laneM) * 32 + laneK;

  const int nIter = K >> 5;
  for (int it = 0; it < nIter; ++it) {
    gl_lds16(pA0, lA0);
    gl_lds16(pA1, lA1);
    gl_lds16(pB0, lB0);
    gl_lds16(pB1, lB1);
    pA0 += 64; pA1 += 64; pB0 += 64; pB1 += 64;
    __syncthreads();
    bf16x8 af[4], bfr[4];
#pragma unroll
    for (int t = 0; t < 4; ++t) {
      af[t]  = *(const bf16x8*)(aRd + t * 16 * 32);
      bfr[t] = *(const bf16x8*)(bRd + t * 16 * 32);
    }
#pragma unroll
    for (int i = 0; i < 4; ++i)
#pragma unroll
      for (int j = 0; j < 4; ++j)
        acc[i][j] = MFMA16(af[i], bfr[j], acc[i][j]);
    __syncthreads();
  }
}

// ---------- GEMM kernels with fused epilogues ----------

// qkv: C = h @ w_attnT^T + b_attn, scatter to q/k/v [B*H][T][D] bf16
__global__ __launch_bounds__(256) void gemm_qkv(
    const u16* __restrict__ A, const u16* __restrict__ Bt,
    const float* __restrict__ bias,
    u16* __restrict__ qo, u16* __restrict__ ko, u16* __restrict__ vo)
{
  f32x4 acc[4][4];
  int m0 = blockIdx.y * 128, n0 = blockIdx.x * 128;
  gemm_mainloop(A, Bt, 1024, m0, n0, acc);
  const int lane = threadIdx.x & 63, w = threadIdx.x >> 6;
  const int wr = (w >> 1) * 64, wc = (w & 1) * 64;
  const int laneM = lane & 15, q4 = lane >> 4;
#pragma unroll
  for (int ti = 0; ti < 4; ++ti) {
#pragma unroll
    for (int tj = 0; tj < 4; ++tj) {
      int n = n0 + wc + tj * 16 + laneM;
      int which = n >> 10, c = n & 1023;
      int hh = c >> 6, d = c & 63;
      u16* dst = which == 0 ? qo : (which == 1 ? ko : vo);
      float bval = bias[n];
#pragma unroll
      for (int r = 0; r < 4; ++r) {
        int m = m0 + wr + ti * 16 + q4 * 4 + r;
        int b = m >> 10, t = m & 1023;
        dst[((size_t)((b * 16 + hh) * 1024 + t)) * 64 + d] = f2bf(acc[ti][tj][r] + bval);
      }
    }
  }
}

// proj: x2 = (x + y @ w_projT^T + b_proj) * mask[row]
__global__ __launch_bounds__(256) void gemm_proj(
    const u16* __restrict__ A, const u16* __restrict__ Bt,
    const float* __restrict__ bias, const float* __restrict__ xin,
    const float* __restrict__ maskv, float* __restrict__ x2)
{
  f32x4 acc[4][4];
  int m0 = blockIdx.y * 128, n0 = blockIdx.x * 128;
  gemm_mainloop(A, Bt, 1024, m0, n0, acc);
  const int lane = threadIdx.x & 63, w = threadIdx.x >> 6;
  const int wr = (w >> 1) * 64, wc = (w & 1) * 64;
  const int laneM = lane & 15, q4 = lane >> 4;
#pragma unroll
  for (int ti = 0; ti < 4; ++ti) {
#pragma unroll
    for (int tj = 0; tj < 4; ++tj) {
      int n = n0 + wc + tj * 16 + laneM;
      float bval = bias[n];
#pragma unroll
      for (int r = 0; r < 4; ++r) {
        int m = m0 + wr + ti * 16 + q4 * 4 + r;
        float v = xin[(size_t)m * 1024 + n] + acc[ti][tj][r] + bval;
        x2[(size_t)m * 1024 + n] = v * maskv[m];
      }
    }
  }
}

// fc: f = gelu_exact(h2 @ w_fcT^T + b_fc) -> bf16
__global__ __launch_bounds__(256) void gemm_fc(
    const u16* __restrict__ A, const u16* __restrict__ Bt,
    const float* __restrict__ bias, u16* __restrict__ fo)
{
  f32x4 acc[4][4];
  int m0 = blockIdx.y * 128, n0 = blockIdx.x * 128;
  gemm_mainloop(A, Bt, 1024, m0, n0, acc);
  const int lane = threadIdx.x & 63, w = threadIdx.x >> 6;
  const int wr = (w >> 1) * 64, wc = (w & 1) * 64;
  const int laneM = lane & 15, q4 = lane >> 4;
#pragma unroll
  for (int ti = 0; ti < 4; ++ti) {
#pragma unroll
    for (int tj = 0; tj < 4; ++tj) {
      int n = n0 + wc + tj * 16 + laneM;
      float bval = bias[n];
#pragma unroll
      for (int r = 0; r < 4; ++r) {
        int m = m0 + wr + ti * 16 + q4 * 4 + r;
        float v = acc[ti][tj][r] + bval;
        float g = 0.5f * v * (1.f + erff(v * 0.70710678118654752f));
        fo[(size_t)m * 4096 + n] = f2bf(g);
      }
    }
  }
}

// fc2: out = x2 + f @ w_fc2T^T + b_fc2 (f32)
__global__ __launch_bounds__(256) void gemm_fc2(
    const u16* __restrict__ A, const u16* __restrict__ Bt,
    const float* __restrict__ bias, const float* __restrict__ x2,
    float* __restrict__ xo)
{
  f32x4 acc[4][4];
  int m0 = blockIdx.y * 128, n0 = blockIdx.x * 128;
  gemm_mainloop(A, Bt, 4096, m0, n0, acc);
  const int lane = threadIdx.x & 63, w = threadIdx.x >> 6;
  const int wr = (w >> 1) * 64, wc = (w & 1) * 64;
  const int laneM = lane & 15, q4 = lane >> 4;
#pragma unroll
  for (int ti = 0; ti < 4; ++ti) {
#pragma unroll
    for (int tj = 0; tj < 4; ++tj) {
      int n = n0 + wc + tj * 16 + laneM;
      float bval = bias[n];
#pragma unroll
      for (int r = 0; r < 4; ++r) {
        int m = m0 + wr + ti * 16 + q4 * 4 + r;
        xo[(size_t)m * 1024 + n] = x2[(size_t)m * 1024 + n] + acc[ti][tj][r] + bval;
      }
    }
  }
}

// ---------- attention: two-pass flash, one block per (b,h,64-query tile) ----------

__global__ __launch_bounds__(256) void attn_fwd(
    const u16* __restrict__ qb, const u16* __restrict__ kb, const u16* __restrict__ vb,
    u16* __restrict__ yb, float* __restrict__ part)
{
  const int bh = blockIdx.y;             // b*16 + h
  const int qbi = blockIdx.x;            // 0..15
  const int b = bh >> 4, h = bh & 15;
  const int tid = threadIdx.x, lane = tid & 63, w = tid >> 6;
  const int q0 = qbi * 64;
  const int laneM = lane & 15, q4 = lane >> 4;
  const float scale = 0.125f;            // 1/sqrt(64)

  __shared__ __align__(16) u16 lK[64 * 72];   // [key][d], rows padded to 72
  __shared__ __align__(16) u16 lV[64 * 72];   // [d][key] (transposed), padded
  __shared__ __align__(16) u16 lP[4][16 * 72];

  // Q A-fragments: lane holds Q[qw + laneM][q4*8 + j (+32)]
  const u16* qrow = qb + ((size_t)(bh * 1024 + q0 + w * 16 + laneM)) * 64 + q4 * 8;
  bf16x8 qf0 = *(const bf16x8*)qrow;
  bf16x8 qf1 = *(const bf16x8*)(qrow + 32);

  float mrow[4] = {-1e30f, -1e30f, -1e30f, -1e30f};
  float lrow[4] = {0.f, 0.f, 0.f, 0.f};
  const int nkt = qbi + 1;

  // ---- pass 1: row max + denominator ----
  for (int kt = 0; kt < nkt; ++kt) {
#pragma unroll
    for (int i = 0; i < 2; ++i) {
      int g = tid + i * 256;
      int row = g >> 3;
      int c8 = (g & 7) * 8;
      const u16* ksrc = kb + ((size_t)(bh * 1024 + kt * 64 + row)) * 64 + c8;
      *(uint4*)&lK[row * 72 + c8] = *(const uint4*)ksrc;
      uint4 vv = *(const uint4*)(vb + ((size_t)(bh * 1024 + kt * 64 + row)) * 64 + c8);
      const u16* vs = (const u16*)&vv;
#pragma unroll
      for (int j = 0; j < 8; ++j) lV[(c8 + j) * 72 + row] = vs[j];
    }
    __syncthreads();
    f32x4 s[4];
#pragma unroll
    for (int tj = 0; tj < 4; ++tj) {
      const u16* kp = &lK[(tj * 16 + laneM) * 72 + q4 * 8];
      bf16x8 k0 = *(const bf16x8*)kp;
      bf16x8 k1 = *(const bf16x8*)(kp + 32);
      f32x4 z = {0.f, 0.f, 0.f, 0.f};
      z = MFMA16(qf0, k0, z);
      z = MFMA16(qf1, k1, z);
      s[tj] = z;
    }
#pragma unroll
    for (int r = 0; r < 4; ++r) {
      int qg = q0 + w * 16 + q4 * 4 + r;
      float sv[4]; float mx = -1e30f;
#pragma unroll
      for (int tj = 0; tj < 4; ++tj) {
        int kc = kt * 64 + tj * 16 + laneM;
        float v = s[tj][r] * scale;
        v = (kc <= qg) ? v : -1e30f;
        sv[tj] = v; mx = fmaxf(mx, v);
      }
#pragma unroll
      for (int o = 1; o < 16; o <<= 1) mx = fmaxf(mx, __shfl_xor(mx, o));
      float mn = fmaxf(mrow[r], mx);
      float sum = 0.f;
#pragma unroll
      for (int tj = 0; tj < 4; ++tj) sum += __expf(sv[tj] - mn);
#pragma unroll
      for (int o = 1; o < 16; o <<= 1) sum += __shfl_xor(sum, o);
      lrow[r] = lrow[r] * __expf(mrow[r] - mn) + sum;
      mrow[r] = mn;
    }
    __syncthreads();
  }

  float linv[4];
#pragma unroll
  for (int r = 0; r < 4; ++r) linv[r] = 1.f / lrow[r];

  // ---- pass 2: probabilities, importance, O = P @ V ----
  f32x4 o_[4];
#pragma unroll
  for (int dt = 0; dt < 4; ++dt) o_[dt] = f32x4{0.f, 0.f, 0.f, 0.f};

  for (int kt = 0; kt < nkt; ++kt) {
#pragma unroll
    for (int i = 0; i < 2; ++i) {
      int g = tid + i * 256;
      int row = g >> 3;
      int c8 = (g & 7) * 8;
      const u16* ksrc = kb + ((size_t)(bh * 1024 + kt * 64 + row)) * 64 + c8;
      *(uint4*)&lK[row * 72 + c8] = *(const uint4*)ksrc;
      uint4 vv = *(const uint4*)(vb + ((size_t)(bh * 1024 + kt * 64 + row)) * 64 + c8);
      const u16* vs = (const u16*)&vv;
#pragma unroll
      for (int j = 0; j < 8; ++j) lV[(c8 + j) * 72 + row] = vs[j];
    }
    __syncthreads();
    f32x4 s[4];
#pragma unroll
    for (int tj = 0; tj < 4; ++tj) {
      const u16* kp = &lK[(tj * 16 + laneM) * 72 + q4 * 8];
      bf16x8 k0 = *(const bf16x8*)kp;
      bf16x8 k1 = *(const bf16x8*)(kp + 32);
      f32x4 z = {0.f, 0.f, 0.f, 0.f};
      z = MFMA16(qf0, k0, z);
      z = MFMA16(qf1, k1, z);
      s[tj] = z;
    }
    u16* lPw = &lP[w][0];
#pragma unroll
    for (int tj = 0; tj < 4; ++tj) {
      float pv[4];
#pragma unroll
      for (int r = 0; r < 4; ++r) {
        int qg = q0 + w * 16 + q4 * 4 + r;
        int kc = kt * 64 + tj * 16 + laneM;
        float v = s[tj][r] * scale;
        v = (kc <= qg) ? v : -1e30f;
        pv[r] = __expf(v - mrow[r]) * linv[r];
      }
      float cs = pv[0] + pv[1] + pv[2] + pv[3];
      cs += __shfl_xor(cs, 16);
      cs += __shfl_xor(cs, 32);
      if (lane < 16)
        atomicAdd(&part[(size_t)bh * 1024 + kt * 64 + tj * 16 + lane], cs);
#pragma unroll
      for (int r = 0; r < 4; ++r)
        lPw[(q4 * 4 + r) * 72 + tj * 16 + laneM] = f2bf(pv[r]);
    }
    __syncthreads();
#pragma unroll
    for (int ss = 0; ss < 2; ++ss) {
      bf16x8 pf = *(const bf16x8*)&lP[w][laneM * 72 + ss * 32 + q4 * 8];
#pragma unroll
      for (int dt = 0; dt < 4; ++dt) {
        bf16x8 vf = *(const bf16x8*)&lV[(dt * 16 + laneM) * 72 + ss * 32 + q4 * 8];
        o_[dt] = MFMA16(pf, vf, o_[dt]);
      }
    }
    __syncthreads();
  }

  // write y: [B][T][C], c = h*64 + d
#pragma unroll
  for (int dt = 0; dt < 4; ++dt)
#pragma unroll
    for (int r = 0; r < 4; ++r) {
      int qg = q0 + w * 16 + q4 * 4 + r;
      yb[((size_t)(b * 1024 + qg)) * 1024 + h * 64 + dt * 16 + laneM] = f2bf(o_[dt][r]);
    }
}

// ---------- importance -> mask ----------

__global__ __launch_bounds__(256) void finalize_mask(
    const float* __restrict__ part, const float* __restrict__ amask,
    const float* __restrict__ thr, float* __restrict__ mask_ws,
    float* __restrict__ out_mask, float* __restrict__ out_loss)
{
  int i = blockIdx.x * 256 + threadIdx.x;
  if (i >= 4096) return;
  int b = i >> 10;
  int t = i & 1023;
  float s = 0.f;
#pragma unroll
  for (int hh = 0; hh < 16; ++hh) s += part[(size_t)(b * 16 + hh) * 1024 + t];
  float imp = s * (1.0f / 16384.0f);
  float mv = (imp >= thr[0]) ? amask[i] : 0.f;
  mask_ws[i] = mv;
  out_mask[i] = mv;
  if (i == 0) out_loss[0] = 0.f;
}

// ---------- host ----------

extern "C" void kernel_launch(void* const* d_in, const int* in_sizes, int n_in,
                              void* d_out, int out_size, void* d_ws, size_t ws_size,
                              hipStream_t stream) {
  const float* x      = (const float*)d_in[0];
  const float* amask  = (const float*)d_in[1];
  const float* ln1w   = (const float*)d_in[2];
  const float* ln1b   = (const float*)d_in[3];
  const float* w_attn = (const float*)d_in[4];
  const float* b_attn = (const float*)d_in[5];
  const float* w_proj = (const float*)d_in[6];
  const float* b_proj = (const float*)d_in[7];
  const float* thr    = (const float*)d_in[8];
  const float* ln2w   = (const float*)d_in[9];
  const float* ln2b   = (const float*)d_in[10];
  const float* w_fc   = (const float*)d_in[11];
  const float* b_fc   = (const float*)d_in[12];
  const float* w_fc2  = (const float*)d_in[13];
  const float* b_fc2  = (const float*)d_in[14];
  float* out = (float*)d_out;

  char* ws = (char*)d_ws;
  size_t off = 0;
  auto alloc = [&](size_t bytes) -> char* {
    char* p = ws + off;
    off += (bytes + 255) & ~(size_t)255;
    return p;
  };
  u16* wattnT = (u16*)alloc((size_t)3072 * 1024 * 2);
  u16* wprojT = (u16*)alloc((size_t)1024 * 1024 * 2);
  u16* wfcT   = (u16*)alloc((size_t)4096 * 1024 * 2);
  u16* wfc2T  = (u16*)alloc((size_t)1024 * 4096 * 2);
  u16* hbuf   = (u16*)alloc((size_t)4096 * 1024 * 2);
  u16* qbuf   = (u16*)alloc((size_t)64 * 1024 * 64 * 2);
  u16* kbuf   = (u16*)alloc((size_t)64 * 1024 * 64 * 2);
  u16* vbuf   = (u16*)alloc((size_t)64 * 1024 * 64 * 2);
  u16* ybuf   = (u16*)alloc((size_t)4096 * 1024 * 2);
  float* part = (float*)alloc((size_t)64 * 1024 * 4);
  float* maskws = (float*)alloc((size_t)4096 * 4);
  float* x2   = (float*)alloc((size_t)4096 * 1024 * 4);
  u16* h2     = (u16*)alloc((size_t)4096 * 1024 * 2);
  u16* fbuf   = (u16*)alloc((size_t)4096 * 4096 * 2);

  dim3 tb(32, 8);
  transpose_to_bf16<<<dim3(96, 32),  tb, 0, stream>>>(w_attn, wattnT, 1024, 3072);
  transpose_to_bf16<<<dim3(32, 32),  tb, 0, stream>>>(w_proj, wprojT, 1024, 1024);
  transpose_to_bf16<<<dim3(128, 32), tb, 0, stream>>>(w_fc,   wfcT,   1024, 4096);
  transpose_to_bf16<<<dim3(32, 128), tb, 0, stream>>>(w_fc2,  wfc2T,  4096, 1024);

  hipMemsetAsync(part, 0, (size_t)64 * 1024 * 4, stream);

  ln_bf16<<<4096, 256, 0, stream>>>(x, ln1w, ln1b, hbuf);

  gemm_qkv<<<dim3(24, 32), 256, 0, stream>>>(hbuf, wattnT, b_attn, qbuf, kbuf, vbuf);

  attn_fwd<<<dim3(16, 64), 256, 0, stream>>>(qbuf, kbuf, vbuf, ybuf, part);

  finalize_mask<<<16, 256, 0, stream>>>(part, amask, thr, maskws,
                                        out + 4194304, out + 4198400);

  gemm_proj<<<dim3(8, 32), 256, 0, stream>>>(ybuf, wprojT, b_proj, x, maskws, x2);

  ln_bf16<<<4096, 256, 0, stream>>>(x2, ln2w, ln2b, h2);

  gemm_fc<<<dim3(32, 32), 256, 0, stream>>>(h2, wfcT, b_fc, fbuf);

  gemm_fc2<<<dim3(8, 32), 256, 0, stream>>>(fbuf, wfc2T, b_fc2, x2, out);
}

// Round 2
// 418.479 us; speedup vs baseline: 1.2113x; 1.2113x over previous
//
#include <hip/hip_runtime.h>
#include <cstdint>
#include <cstring>

typedef unsigned short u16;
typedef short bf16x8 __attribute__((ext_vector_type(8)));
typedef float f32x4 __attribute__((ext_vector_type(4)));

#define MFMA16(a,b,c) __builtin_amdgcn_mfma_f32_16x16x32_bf16(a,b,c,0,0,0)

// ---------- helpers ----------

__device__ __forceinline__ u16 f2bf(float f) {
  union { float f; uint32_t u; } un; un.f = f;
  uint32_t u = un.u;
  u += 0x7FFFu + ((u >> 16) & 1u);   // RNE
  return (u16)(u >> 16);
}

__device__ __forceinline__ void gl_lds16(const void* g, void* l) {
  __builtin_amdgcn_global_load_lds(
      (__attribute__((address_space(1))) void*)(const_cast<void*>(g)),
      (__attribute__((address_space(3))) void*)l, 16, 0, 0);
}

// ---------- weight transpose + f32->bf16 : W[K][N] -> Wt[N][K] ----------

__global__ __launch_bounds__(256) void transpose_to_bf16(
    const float* __restrict__ W, u16* __restrict__ Wt, int K, int N)
{
  __shared__ float tile[32][33];
  int kt = blockIdx.y * 32, nt = blockIdx.x * 32;
  int tx = threadIdx.x, ty = threadIdx.y;          // (32, 8)
#pragma unroll
  for (int i = 0; i < 4; ++i)
    tile[ty + i * 8][tx] = W[(size_t)(kt + ty + i * 8) * N + nt + tx];
  __syncthreads();
#pragma unroll
  for (int i = 0; i < 4; ++i)
    Wt[(size_t)(nt + ty + i * 8) * K + kt + tx] = f2bf(tile[tx][ty + i * 8]);
}

// ---------- LayerNorm (f32 in -> bf16 out), one block per row of 1024 ----------

__global__ __launch_bounds__(256) void ln_bf16(
    const float* __restrict__ x, const float* __restrict__ wt,
    const float* __restrict__ bs, u16* __restrict__ out)
{
  int row = blockIdx.x;
  int tid = threadIdx.x, lane = tid & 63, w = tid >> 6;
  const float* xr = x + (size_t)row * 1024;
  float4 v = *(const float4*)(xr + tid * 4);
  float s = v.x + v.y + v.z + v.w;
  float sq = v.x * v.x + v.y * v.y + v.z * v.z + v.w * v.w;
#pragma unroll
  for (int o = 1; o < 64; o <<= 1) { s += __shfl_xor(s, o); sq += __shfl_xor(sq, o); }
  __shared__ float ls[4], lq[4];
  if (lane == 0) { ls[w] = s; lq[w] = sq; }
  __syncthreads();
  s = ls[0] + ls[1] + ls[2] + ls[3];
  sq = lq[0] + lq[1] + lq[2] + lq[3];
  float mu = s * (1.f / 1024.f);
  float var = sq * (1.f / 1024.f) - mu * mu;
  float rstd = rsqrtf(var + 1e-5f);
  float4 wv = *(const float4*)(wt + tid * 4);
  float4 bv = *(const float4*)(bs + tid * 4);
  ushort4 o4;
  o4.x = f2bf((v.x - mu) * rstd * wv.x + bv.x);
  o4.y = f2bf((v.y - mu) * rstd * wv.y + bv.y);
  o4.z = f2bf((v.z - mu) * rstd * wv.z + bv.z);
  o4.w = f2bf((v.w - mu) * rstd * wv.w + bv.w);
  *(ushort4*)(out + (size_t)row * 1024 + tid * 4) = o4;
}

// ---------- GEMM mainloop: C(128x128) = A[M][K] @ Bt[N][K]^T, bf16 MFMA ----------

__device__ __forceinline__ void gemm_mainloop(
    const u16* __restrict__ A, const u16* __restrict__ Bt,
    int K, int m0, int n0, f32x4 acc[4][4])
{
  __shared__ __align__(16) u16 lA[128 * 32];
  __shared__ __align__(16) u16 lB[128 * 32];

  const int tid = threadIdx.x;
  const int lane = tid & 63;
  const int w = tid >> 6;
  const int wr = (w >> 1) * 64;
  const int wc = (w & 1) * 64;
  const int laneM = lane & 15;
  const int laneK = (lane >> 4) * 8;

#pragma unroll
  for (int i = 0; i < 4; ++i)
#pragma unroll
    for (int j = 0; j < 4; ++j)
      acc[i][j] = f32x4{0.f, 0.f, 0.f, 0.f};

  const int off0 = w * 1024 + lane * 16;
  const int off1 = off0 + 4096;
  const int rA0 = off0 >> 6, cb0 = off0 & 63;
  const int rA1 = off1 >> 6, cb1 = off1 & 63;

  const size_t strideA = (size_t)K * 2;
  const char* gA = (const char*)(A + (size_t)m0 * K);
  const char* gB = (const char*)(Bt + (size_t)n0 * K);
  const char* pA0 = gA + (size_t)rA0 * strideA + cb0;
  const char* pA1 = gA + (size_t)rA1 * strideA + cb1;
  const char* pB0 = gB + (size_t)rA0 * strideA + cb0;
  const char* pB1 = gB + (size_t)rA1 * strideA + cb1;
  char* lA0 = (char*)lA + off0;
  char* lA1 = (char*)lA + off1;
  char* lB0 = (char*)lB + off0;
  char* lB1 = (char*)lB + off1;

  const u16* aRd = lA + (wr + laneM) * 32 + laneK;
  const u16* bRd = lB + (wc + laneM) * 32 + laneK;

  const int nIter = K >> 5;
  for (int it = 0; it < nIter; ++it) {
    gl_lds16(pA0, lA0);
    gl_lds16(pA1, lA1);
    gl_lds16(pB0, lB0);
    gl_lds16(pB1, lB1);
    pA0 += 64; pA1 += 64; pB0 += 64; pB1 += 64;
    __syncthreads();
    bf16x8 af[4], bfr[4];
#pragma unroll
    for (int t = 0; t < 4; ++t) {
      af[t]  = *(const bf16x8*)(aRd + t * 16 * 32);
      bfr[t] = *(const bf16x8*)(bRd + t * 16 * 32);
    }
#pragma unroll
    for (int i = 0; i < 4; ++i)
#pragma unroll
      for (int j = 0; j < 4; ++j)
        acc[i][j] = MFMA16(af[i], bfr[j], acc[i][j]);
    __syncthreads();
  }
}

// ---------- GEMM kernels with fused epilogues ----------

// qkv: C = h @ w_attnT^T + b_attn; q,k -> [bh][t][d]; v -> [bh][d][t] (V^T)
__global__ __launch_bounds__(256) void gemm_qkv(
    const u16* __restrict__ A, const u16* __restrict__ Bt,
    const float* __restrict__ bias,
    u16* __restrict__ qo, u16* __restrict__ ko, u16* __restrict__ vo)
{
  f32x4 acc[4][4];
  int m0 = blockIdx.y * 128, n0 = blockIdx.x * 128;
  gemm_mainloop(A, Bt, 1024, m0, n0, acc);
  const int lane = threadIdx.x & 63, w = threadIdx.x >> 6;
  const int wr = (w >> 1) * 64, wc = (w & 1) * 64;
  const int laneM = lane & 15, q4 = lane >> 4;
  const int which = (n0 >> 10);                 // uniform per block
#pragma unroll
  for (int ti = 0; ti < 4; ++ti) {
#pragma unroll
    for (int tj = 0; tj < 4; ++tj) {
      int n = n0 + wc + tj * 16 + laneM;
      int c = n & 1023;
      int hh = c >> 6, d = c & 63;
      float bval = bias[n];
      if (which == 2) {
        // V^T: 4 consecutive t per lane -> packed 8B store
        int m0r = m0 + wr + ti * 16 + q4 * 4;
        int b = m0r >> 10, t0 = m0r & 1023;
        ushort4 o4;
        o4.x = f2bf(acc[ti][tj][0] + bval);
        o4.y = f2bf(acc[ti][tj][1] + bval);
        o4.z = f2bf(acc[ti][tj][2] + bval);
        o4.w = f2bf(acc[ti][tj][3] + bval);
        *(ushort4*)&vo[((size_t)((b * 16 + hh) * 64 + d)) * 1024 + t0] = o4;
      } else {
        u16* dst = (which == 0) ? qo : ko;
#pragma unroll
        for (int r = 0; r < 4; ++r) {
          int m = m0 + wr + ti * 16 + q4 * 4 + r;
          int b = m >> 10, t = m & 1023;
          dst[((size_t)((b * 16 + hh) * 1024 + t)) * 64 + d] = f2bf(acc[ti][tj][r] + bval);
        }
      }
    }
  }
}

// proj: x2 = (x + y @ w_projT^T + b_proj) * mask[row]
__global__ __launch_bounds__(256) void gemm_proj(
    const u16* __restrict__ A, const u16* __restrict__ Bt,
    const float* __restrict__ bias, const float* __restrict__ xin,
    const float* __restrict__ maskv, float* __restrict__ x2)
{
  f32x4 acc[4][4];
  int m0 = blockIdx.y * 128, n0 = blockIdx.x * 128;
  gemm_mainloop(A, Bt, 1024, m0, n0, acc);
  const int lane = threadIdx.x & 63, w = threadIdx.x >> 6;
  const int wr = (w >> 1) * 64, wc = (w & 1) * 64;
  const int laneM = lane & 15, q4 = lane >> 4;
#pragma unroll
  for (int ti = 0; ti < 4; ++ti) {
#pragma unroll
    for (int tj = 0; tj < 4; ++tj) {
      int n = n0 + wc + tj * 16 + laneM;
      float bval = bias[n];
#pragma unroll
      for (int r = 0; r < 4; ++r) {
        int m = m0 + wr + ti * 16 + q4 * 4 + r;
        float v = xin[(size_t)m * 1024 + n] + acc[ti][tj][r] + bval;
        x2[(size_t)m * 1024 + n] = v * maskv[m];
      }
    }
  }
}

// fc: f = gelu_exact(h2 @ w_fcT^T + b_fc) -> bf16
__global__ __launch_bounds__(256) void gemm_fc(
    const u16* __restrict__ A, const u16* __restrict__ Bt,
    const float* __restrict__ bias, u16* __restrict__ fo)
{
  f32x4 acc[4][4];
  int m0 = blockIdx.y * 128, n0 = blockIdx.x * 128;
  gemm_mainloop(A, Bt, 1024, m0, n0, acc);
  const int lane = threadIdx.x & 63, w = threadIdx.x >> 6;
  const int wr = (w >> 1) * 64, wc = (w & 1) * 64;
  const int laneM = lane & 15, q4 = lane >> 4;
#pragma unroll
  for (int ti = 0; ti < 4; ++ti) {
#pragma unroll
    for (int tj = 0; tj < 4; ++tj) {
      int n = n0 + wc + tj * 16 + laneM;
      float bval = bias[n];
#pragma unroll
      for (int r = 0; r < 4; ++r) {
        int m = m0 + wr + ti * 16 + q4 * 4 + r;
        float v = acc[ti][tj][r] + bval;
        float g = 0.5f * v * (1.f + erff(v * 0.70710678118654752f));
        fo[(size_t)m * 4096 + n] = f2bf(g);
      }
    }
  }
}

// fc2: out = x2 + f @ w_fc2T^T + b_fc2 (f32)
__global__ __launch_bounds__(256) void gemm_fc2(
    const u16* __restrict__ A, const u16* __restrict__ Bt,
    const float* __restrict__ bias, const float* __restrict__ x2,
    float* __restrict__ xo)
{
  f32x4 acc[4][4];
  int m0 = blockIdx.y * 128, n0 = blockIdx.x * 128;
  gemm_mainloop(A, Bt, 4096, m0, n0, acc);
  const int lane = threadIdx.x & 63, w = threadIdx.x >> 6;
  const int wr = (w >> 1) * 64, wc = (w & 1) * 64;
  const int laneM = lane & 15, q4 = lane >> 4;
#pragma unroll
  for (int ti = 0; ti < 4; ++ti) {
#pragma unroll
    for (int tj = 0; tj < 4; ++tj) {
      int n = n0 + wc + tj * 16 + laneM;
      float bval = bias[n];
#pragma unroll
      for (int r = 0; r < 4; ++r) {
        int m = m0 + wr + ti * 16 + q4 * 4 + r;
        xo[(size_t)m * 1024 + n] = x2[(size_t)m * 1024 + n] + acc[ti][tj][r] + bval;
      }
    }
  }
}

// ---------- attention: two-pass (l then P/PV/importance), no max subtraction ----------
// Grid: (64 bh, 16 qtiles reversed). V comes in transposed [bh][d][t].

__global__ __launch_bounds__(256) void attn_fwd(
    const u16* __restrict__ qb, const u16* __restrict__ kb, const u16* __restrict__ vtb,
    u16* __restrict__ yb, float* __restrict__ part)
{
  const int bh = blockIdx.x;               // 0..63
  const int qbi = 15 - blockIdx.y;         // heavy blocks dispatched first
  const int b = bh >> 4, h = bh & 15;
  const int tid = threadIdx.x, lane = tid & 63, w = tid >> 6;
  const int q0 = qbi * 64;
  const int laneM = lane & 15, q4 = lane >> 4;
  const float scale = 0.125f;

  __shared__ __align__(16) u16 lK[64 * 72];      // [key][d], pad 72
  __shared__ __align__(16) u16 lV[64 * 72];      // [d][key], pad 72 (from V^T global)
  __shared__ __align__(16) u16 lP[4][16 * 72];   // per-wave P tile, pad 72

  const u16* qrow = qb + ((size_t)(bh * 1024 + q0 + w * 16 + laneM)) * 64 + q4 * 8;
  bf16x8 qf0 = *(const bf16x8*)qrow;
  bf16x8 qf1 = *(const bf16x8*)(qrow + 32);

  const int nkt = qbi + 1;
  const int srow = tid >> 3;               // 0..31
  const int scol = (tid & 7) * 8;          // u16 units, 16B chunks
  const u16* kbase = kb + (size_t)bh * 65536;    // [t][64]
  const u16* vbase = vtb + (size_t)bh * 65536;   // [d][1024]

  // ---- pass 1: denominators only ----
  float lrow[4] = {0.f, 0.f, 0.f, 0.f};
  for (int kt = 0; kt < nkt; ++kt) {
#pragma unroll
    for (int p = 0; p < 2; ++p) {
      int row = srow + p * 32;
      *(uint4*)&lK[row * 72 + scol] =
          *(const uint4*)(kbase + (size_t)(kt * 64 + row) * 64 + scol);
    }
    __syncthreads();
#pragma unroll
    for (int tj = 0; tj < 4; ++tj) {
      const u16* kp = &lK[(tj * 16 + laneM) * 72 + q4 * 8];
      bf16x8 k0 = *(const bf16x8*)kp;
      bf16x8 k1 = *(const bf16x8*)(kp + 32);
      f32x4 z = {0.f, 0.f, 0.f, 0.f};
      z = MFMA16(qf0, k0, z);
      z = MFMA16(qf1, k1, z);
      int kc = kt * 64 + tj * 16 + laneM;
#pragma unroll
      for (int r = 0; r < 4; ++r) {
        int qg = q0 + w * 16 + q4 * 4 + r;
        lrow[r] += (kc <= qg) ? __expf(z[r] * scale) : 0.f;
      }
    }
    __syncthreads();
  }
  float linv[4];
#pragma unroll
  for (int r = 0; r < 4; ++r) {
    float s = lrow[r];
    s += __shfl_xor(s, 1); s += __shfl_xor(s, 2);
    s += __shfl_xor(s, 4); s += __shfl_xor(s, 8);
    linv[r] = 1.f / s;
  }

  // ---- pass 2: P (normalized), importance, O = P @ V ----
  f32x4 o_[4];
#pragma unroll
  for (int dt = 0; dt < 4; ++dt) o_[dt] = f32x4{0.f, 0.f, 0.f, 0.f};

  for (int kt = 0; kt < nkt; ++kt) {
#pragma unroll
    for (int p = 0; p < 2; ++p) {
      int row = srow + p * 32;
      *(uint4*)&lK[row * 72 + scol] =
          *(const uint4*)(kbase + (size_t)(kt * 64 + row) * 64 + scol);
      *(uint4*)&lV[row * 72 + scol] =
          *(const uint4*)(vbase + (size_t)row * 1024 + kt * 64 + scol);
    }
    __syncthreads();
    u16* lPw = &lP[w][0];
#pragma unroll
    for (int tj = 0; tj < 4; ++tj) {
      const u16* kp = &lK[(tj * 16 + laneM) * 72 + q4 * 8];
      bf16x8 k0 = *(const bf16x8*)kp;
      bf16x8 k1 = *(const bf16x8*)(kp + 32);
      f32x4 z = {0.f, 0.f, 0.f, 0.f};
      z = MFMA16(qf0, k0, z);
      z = MFMA16(qf1, k1, z);
      int kc = kt * 64 + tj * 16 + laneM;
      float cs = 0.f;
#pragma unroll
      for (int r = 0; r < 4; ++r) {
        int qg = q0 + w * 16 + q4 * 4 + r;
        float pv = (kc <= qg) ? __expf(z[r] * scale) * linv[r] : 0.f;
        cs += pv;
        lPw[(q4 * 4 + r) * 72 + tj * 16 + laneM] = f2bf(pv);
      }
      cs += __shfl_xor(cs, 16);
      cs += __shfl_xor(cs, 32);
      if (lane < 16)
        atomicAdd(&part[(size_t)bh * 1024 + kt * 64 + tj * 16 + lane], cs);
    }
    // PV: lP is per-wave (RAW within wave -> lgkmcnt only, no barrier)
#pragma unroll
    for (int ss = 0; ss < 2; ++ss) {
      bf16x8 pf = *(const bf16x8*)&lP[w][laneM * 72 + ss * 32 + q4 * 8];
#pragma unroll
      for (int dt = 0; dt < 4; ++dt) {
        bf16x8 vf = *(const bf16x8*)&lV[(dt * 16 + laneM) * 72 + ss * 32 + q4 * 8];
        o_[dt] = MFMA16(pf, vf, o_[dt]);
      }
    }
    __syncthreads();
  }

  // write y: [B][T][C], c = h*64 + d  (O already normalized)
#pragma unroll
  for (int dt = 0; dt < 4; ++dt)
#pragma unroll
    for (int r = 0; r < 4; ++r) {
      int qg = q0 + w * 16 + q4 * 4 + r;
      yb[((size_t)(b * 1024 + qg)) * 1024 + h * 64 + dt * 16 + laneM] = f2bf(o_[dt][r]);
    }
}

// ---------- importance -> mask ----------

__global__ __launch_bounds__(256) void finalize_mask(
    const float* __restrict__ part, const float* __restrict__ amask,
    const float* __restrict__ thr, float* __restrict__ mask_ws,
    float* __restrict__ out_mask, float* __restrict__ out_loss)
{
  int i = blockIdx.x * 256 + threadIdx.x;
  if (i >= 4096) return;
  int b = i >> 10;
  int t = i & 1023;
  float s = 0.f;
#pragma unroll
  for (int hh = 0; hh < 16; ++hh) s += part[(size_t)(b * 16 + hh) * 1024 + t];
  float imp = s * (1.0f / 16384.0f);
  float mv = (imp >= thr[0]) ? amask[i] : 0.f;
  mask_ws[i] = mv;
  out_mask[i] = mv;
  if (i == 0) out_loss[0] = 0.f;
}

// ---------- host ----------

extern "C" void kernel_launch(void* const* d_in, const int* in_sizes, int n_in,
                              void* d_out, int out_size, void* d_ws, size_t ws_size,
                              hipStream_t stream) {
  const float* x      = (const float*)d_in[0];
  const float* amask  = (const float*)d_in[1];
  const float* ln1w   = (const float*)d_in[2];
  const float* ln1b   = (const float*)d_in[3];
  const float* w_attn = (const float*)d_in[4];
  const float* b_attn = (const float*)d_in[5];
  const float* w_proj = (const float*)d_in[6];
  const float* b_proj = (const float*)d_in[7];
  const float* thr    = (const float*)d_in[8];
  const float* ln2w   = (const float*)d_in[9];
  const float* ln2b   = (const float*)d_in[10];
  const float* w_fc   = (const float*)d_in[11];
  const float* b_fc   = (const float*)d_in[12];
  const float* w_fc2  = (const float*)d_in[13];
  const float* b_fc2  = (const float*)d_in[14];
  float* out = (float*)d_out;

  char* ws = (char*)d_ws;
  size_t off = 0;
  auto alloc = [&](size_t bytes) -> char* {
    char* p = ws + off;
    off += (bytes + 255) & ~(size_t)255;
    return p;
  };
  u16* wattnT = (u16*)alloc((size_t)3072 * 1024 * 2);
  u16* wprojT = (u16*)alloc((size_t)1024 * 1024 * 2);
  u16* wfcT   = (u16*)alloc((size_t)4096 * 1024 * 2);
  u16* wfc2T  = (u16*)alloc((size_t)1024 * 4096 * 2);
  u16* hbuf   = (u16*)alloc((size_t)4096 * 1024 * 2);
  u16* qbuf   = (u16*)alloc((size_t)64 * 1024 * 64 * 2);
  u16* kbuf   = (u16*)alloc((size_t)64 * 1024 * 64 * 2);
  u16* vtbuf  = (u16*)alloc((size_t)64 * 64 * 1024 * 2);   // V^T [bh][d][t]
  u16* ybuf   = (u16*)alloc((size_t)4096 * 1024 * 2);
  float* part = (float*)alloc((size_t)64 * 1024 * 4);
  float* maskws = (float*)alloc((size_t)4096 * 4);
  float* x2   = (float*)alloc((size_t)4096 * 1024 * 4);
  u16* h2     = (u16*)alloc((size_t)4096 * 1024 * 2);
  u16* fbuf   = (u16*)alloc((size_t)4096 * 4096 * 2);

  dim3 tb(32, 8);
  transpose_to_bf16<<<dim3(96, 32),  tb, 0, stream>>>(w_attn, wattnT, 1024, 3072);
  transpose_to_bf16<<<dim3(32, 32),  tb, 0, stream>>>(w_proj, wprojT, 1024, 1024);
  transpose_to_bf16<<<dim3(128, 32), tb, 0, stream>>>(w_fc,   wfcT,   1024, 4096);
  transpose_to_bf16<<<dim3(32, 128), tb, 0, stream>>>(w_fc2,  wfc2T,  4096, 1024);

  hipMemsetAsync(part, 0, (size_t)64 * 1024 * 4, stream);

  ln_bf16<<<4096, 256, 0, stream>>>(x, ln1w, ln1b, hbuf);

  gemm_qkv<<<dim3(24, 32), 256, 0, stream>>>(hbuf, wattnT, b_attn, qbuf, kbuf, vtbuf);

  attn_fwd<<<dim3(64, 16), 256, 0, stream>>>(qbuf, kbuf, vtbuf, ybuf, part);

  finalize_mask<<<16, 256, 0, stream>>>(part, amask, thr, maskws,
                                        out + 4194304, out + 4198400);

  gemm_proj<<<dim3(8, 32), 256, 0, stream>>>(ybuf, wprojT, b_proj, x, maskws, x2);

  ln_bf16<<<4096, 256, 0, stream>>>(x2, ln2w, ln2b, h2);

  gemm_fc<<<dim3(32, 32), 256, 0, stream>>>(h2, wfcT, b_fc, fbuf);

  gemm_fc2<<<dim3(8, 32), 256, 0, stream>>>(fbuf, wfc2T, b_fc2, x2, out);
}